// Round 5
// baseline (1266.415 us; speedup 1.0000x reference)
//
#include <hip/hip_runtime.h>
#include <stdint.h>

#define NNODES 100000
#define NEDGES 100000
#define DIM    256
#define NCH    4          // 2 side + 2 rel
#define ET     64         // edges per block
#define EH     32         // edges per half-tile
#define RSTRIDE 260       // u32 per staged row (256 + 4 pad)

typedef short bf16x8 __attribute__((ext_vector_type(8)));
typedef float f32x4  __attribute__((ext_vector_type(4)));
typedef uint32_t u32x4 __attribute__((ext_vector_type(4)));

__device__ __forceinline__ short f2bf_rn(float x) {
    union { float f; uint32_t u; } v; v.f = x;
    uint32_t u = v.u;
    uint32_t r = u + 0x7fffu + ((u >> 16) & 1u);
    return (short)(r >> 16);
}
__device__ __forceinline__ float bf2f(short s) {
    union { float f; uint32_t u; } v;
    v.u = ((uint32_t)(unsigned short)s) << 16;
    return v.f;
}

// ---------------------------------------------------------------------------
// Prep: fused/transposed channel matrices in MFMA B-fragment order, split
// hi/lo bf16. idx = (((c*8+kc)*16+ft)*64+lane)*8+j,
// k = kc*32 + (lane>>4)*8 + j, f = ft*16 + (lane&15).
//   M_c[f][k] = d_side[c][f]*R_W[f][k]*d_side[c][k]   (c < 2)
//             = W_rel[c-2][f][k]                       (c >= 2)
// ---------------------------------------------------------------------------
__global__ void prep_B(const float* __restrict__ RW,
                       const float* __restrict__ dside,
                       const float* __restrict__ Wrel,
                       short* __restrict__ Bh, short* __restrict__ Bl) {
    int t = blockIdx.x * blockDim.x + threadIdx.x;
    if (t >= NCH * 8 * 16 * 64) return;
    int lane = t & 63;
    int ft   = (t >> 6) & 15;
    int kc   = (t >> 10) & 7;
    int c    = t >> 13;
    int quad = lane >> 4, col = lane & 15;
    int f     = ft * 16 + col;
    int kbase = kc * 32 + quad * 8;

    bf16x8 vh, vl;
#pragma unroll
    for (int j = 0; j < 8; ++j) {
        int k = kbase + j;
        float val;
        if (c < 2) {
            val = dside[c * DIM + f] * RW[f * DIM + k] * dside[c * DIM + k];
        } else {
            val = Wrel[(size_t)(c - 2) * DIM * DIM + f * DIM + k];
        }
        short hi = f2bf_rn(val);
        float rem = val - bf2f(hi);
        vh[j] = hi;
        vl[j] = f2bf_rn(rem);
    }
    ((bf16x8*)Bh)[t] = vh;
    ((bf16x8*)Bl)[t] = vl;
}

// ---------------------------------------------------------------------------
// Fused edge kernel, half-tile structure for occupancy:
//   per (channel, 64-edge tile), two sequential 32-edge halves:
//     stage:  8 rows/wave, one fully-coalesced 1KB dwordx4 load per row,
//             split-bf16 packed u32(hi|lo), ds_write row-major (+16B pad)
//     K-loop: A frags from LDS, B frags from pre-swizzled L2-resident table,
//             3-term split-bf16 MFMA, acc = 2 mt x 4 ft (32 VGPRs)
//     epilogue: score[e] = sum_f (C[e][f]+bias[f]) * V[e][f], V = exact f32.
// LDS ~35 KB -> 4 blocks/CU (vs 2 in round 4).
// ---------------------------------------------------------------------------
__global__ __launch_bounds__(256, 4)
void edge_kernel(const float* __restrict__ hmat,
                 const int* __restrict__ src_idx,
                 const int* __restrict__ dst_idx,
                 const float* __restrict__ brel,
                 const short* __restrict__ Bh_sw,
                 const short* __restrict__ Bl_sw,
                 float* __restrict__ out) {
    const int c    = blockIdx.y;
    const int e0   = blockIdx.x * ET;
    const int tid  = threadIdx.x;
    const int w    = tid >> 6;
    const int lane = tid & 63;
    const int quad = lane >> 4, col = lane & 15;

    __shared__ uint32_t s_row[EH * RSTRIDE];   // 33,280 B
    __shared__ uint32_t s_src[ET];
    __shared__ uint32_t s_dst[ET];
    __shared__ float    red[4][EH];

    if (tid < ET) {
        int idx = e0 + tid;
        int si = 0, di = 0;
        if (idx < NEDGES) {
            si = src_idx[(size_t)c * NEDGES + idx];
            di = dst_idx[(size_t)c * NEDGES + idx];
        }
        s_src[tid] = (uint32_t)si;
        s_dst[tid] = (uint32_t)di;
    }
    __syncthreads();

    const bf16x8* Bh = (const bf16x8*)Bh_sw;
    const bf16x8* Bl = (const bf16x8*)Bl_sw;

    for (int H = 0; H < 2; ++H) {
        // ---- Stage: wave w loads local rows w*8..w*8+7 (coalesced 1KB) ----
#pragma unroll
        for (int i = 0; i < 8; ++i) {
            int lr = w * 8 + i;
            const float* rb = hmat + (size_t)s_src[H * EH + lr] * DIM;
            f32x4 x = *(const f32x4*)(rb + lane * 4);
            u32x4 o;
#pragma unroll
            for (int j = 0; j < 4; ++j) {
                short hi = f2bf_rn(x[j]);
                short lo = f2bf_rn(x[j] - bf2f(hi));
                o[j] = ((uint32_t)(unsigned short)hi << 16) | (uint32_t)(unsigned short)lo;
            }
            *(u32x4*)&s_row[lr * RSTRIDE + lane * 4] = o;
        }
        __syncthreads();

        // ---- K-loop ----
        f32x4 acc[2][4];
#pragma unroll
        for (int i = 0; i < 2; ++i)
#pragma unroll
            for (int j = 0; j < 4; ++j) acc[i][j] = (f32x4){0.f, 0.f, 0.f, 0.f};

#pragma unroll
        for (int kc = 0; kc < 8; ++kc) {
            bf16x8 Ah[2], Al[2];
#pragma unroll
            for (int mt = 0; mt < 2; ++mt) {
                int lr = mt * 16 + col;
                const uint32_t* p = &s_row[lr * RSTRIDE + kc * 32 + quad * 8];
                u32x4 q0 = *(const u32x4*)p;
                u32x4 q1 = *(const u32x4*)(p + 4);
                bf16x8 ah, al;
#pragma unroll
                for (int j = 0; j < 4; ++j) {
                    ah[j]     = (short)(q0[j] >> 16);
                    al[j]     = (short)(q0[j] & 0xffffu);
                    ah[4 + j] = (short)(q1[j] >> 16);
                    al[4 + j] = (short)(q1[j] & 0xffffu);
                }
                Ah[mt] = ah;
                Al[mt] = al;
            }
            int fb = ((c * 8 + kc) * 16 + w * 4) * 64 + lane;
#pragma unroll
            for (int ft = 0; ft < 4; ++ft) {
                bf16x8 bh = Bh[fb + ft * 64];
                bf16x8 bl = Bl[fb + ft * 64];
#pragma unroll
                for (int mt = 0; mt < 2; ++mt) {
                    acc[mt][ft] = __builtin_amdgcn_mfma_f32_16x16x32_bf16(Ah[mt], bh, acc[mt][ft], 0, 0, 0);
                    acc[mt][ft] = __builtin_amdgcn_mfma_f32_16x16x32_bf16(Ah[mt], bl, acc[mt][ft], 0, 0, 0);
                    acc[mt][ft] = __builtin_amdgcn_mfma_f32_16x16x32_bf16(Al[mt], bh, acc[mt][ft], 0, 0, 0);
                }
            }
        }

        // ---- Epilogue: psum over this half's 32 edges ----
        // C/D layout: row(e) = quad*4 + reg, col(f) = lane&15.
        float psum[2][4];
#pragma unroll
        for (int mt = 0; mt < 2; ++mt) {
#pragma unroll
            for (int r = 0; r < 4; ++r) {
                int el = mt * 16 + quad * 4 + r;          // local row in half
                size_t roff = (size_t)s_dst[H * EH + el] * DIM;
                float s = 0.f;
#pragma unroll
                for (int ft = 0; ft < 4; ++ft) {
                    int f = w * 64 + ft * 16 + col;
                    float bias = (c >= 2) ? brel[(size_t)(c - 2) * DIM + f] : 0.f;
                    float v = hmat[roff + f];
                    s += (acc[mt][ft][r] + bias) * v;
                }
                psum[mt][r] = s;
            }
        }

        // Reduce across the 16 f-columns (xor lane bits 0..3)
#pragma unroll
        for (int off = 1; off < 16; off <<= 1) {
#pragma unroll
            for (int mt = 0; mt < 2; ++mt)
#pragma unroll
                for (int r = 0; r < 4; ++r)
                    psum[mt][r] += __shfl_xor(psum[mt][r], off, 64);
        }
        if (col == 0) {
#pragma unroll
            for (int mt = 0; mt < 2; ++mt)
#pragma unroll
                for (int r = 0; r < 4; ++r)
                    red[w][mt * 16 + quad * 4 + r] = psum[mt][r];
        }
        __syncthreads();

        if (tid < EH) {
            int idx = e0 + H * EH + tid;
            if (idx < NEDGES) {
                float s = red[0][tid] + red[1][tid] + red[2][tid] + red[3][tid];
                out[(size_t)c * NEDGES + idx] = s;
            }
        }
        // next half's staging may proceed: s_row reads all completed before
        // the barrier above; red is not touched by staging.
    }
}

extern "C" void kernel_launch(void* const* d_in, const int* in_sizes, int n_in,
                              void* d_out, int out_size, void* d_ws, size_t ws_size,
                              hipStream_t stream) {
    const float* hmat  = (const float*)d_in[0];
    const int*   src   = (const int*)d_in[1];
    const int*   dst   = (const int*)d_in[2];
    const float* RW    = (const float*)d_in[3];
    const float* dside = (const float*)d_in[4];
    const float* Wrel  = (const float*)d_in[5];
    const float* brel  = (const float*)d_in[6];
    float* out = (float*)d_out;

    // Workspace: Bh (512 KB) | Bl (512 KB)
    const size_t nB = (size_t)NCH * DIM * DIM;   // shorts per table
    short* Bh = (short*)d_ws;
    short* Bl = Bh + nB;

    prep_B<<<dim3((NCH * 8 * 16 * 64) / 256), dim3(256), 0, stream>>>(RW, dside, Wrel, Bh, Bl);

    dim3 grid((NEDGES + ET - 1) / ET, NCH);
    edge_kernel<<<grid, dim3(256), 0, stream>>>(hmat, src, dst, brel, Bh, Bl, out);
}

// Round 6
// 355.603 us; speedup vs baseline: 3.5613x; 3.5613x over previous
//
#include <hip/hip_runtime.h>
#include <stdint.h>

#define NNODES 100000
#define NEDGES 100000
#define DIM    256
#define NCH    4          // 2 side + 2 rel
#define ET     64         // edges per block
#define RS     260        // u32 per staged row (256 + 4 pad; 260 % 32 == 4)

typedef short bf16x8 __attribute__((ext_vector_type(8)));
typedef float f32x4  __attribute__((ext_vector_type(4)));
typedef uint32_t u32x4 __attribute__((ext_vector_type(4)));

__device__ __forceinline__ short f2bf_rn(float x) {
    union { float f; uint32_t u; } v; v.f = x;
    uint32_t u = v.u;
    uint32_t r = u + 0x7fffu + ((u >> 16) & 1u);
    return (short)(r >> 16);
}
__device__ __forceinline__ float bf2f(short s) {
    union { float f; uint32_t u; } v;
    v.u = ((uint32_t)(unsigned short)s) << 16;
    return v.f;
}
__device__ __forceinline__ float asf(uint32_t u) {
    union { float f; uint32_t u; } v; v.u = u; return v.f;
}

// ---------------------------------------------------------------------------
// Prep: fused/transposed channel matrices in MFMA B-fragment order, split
// hi/lo bf16. idx = (((c*8+kc)*16+ft)*64+lane)*8+j,
// k = kc*32 + (lane>>4)*8 + j, f = ft*16 + (lane&15).
//   M_c[f][k] = d_side[c][f]*R_W[f][k]*d_side[c][k]   (c < 2)
//             = W_rel[c-2][f][k]                       (c >= 2)
// ---------------------------------------------------------------------------
__global__ void prep_B(const float* __restrict__ RW,
                       const float* __restrict__ dside,
                       const float* __restrict__ Wrel,
                       short* __restrict__ Bh, short* __restrict__ Bl) {
    int t = blockIdx.x * blockDim.x + threadIdx.x;
    if (t >= NCH * 8 * 16 * 64) return;
    int lane = t & 63;
    int ft   = (t >> 6) & 15;
    int kc   = (t >> 10) & 7;
    int c    = t >> 13;
    int quad = lane >> 4, col = lane & 15;
    int f     = ft * 16 + col;
    int kbase = kc * 32 + quad * 8;

    bf16x8 vh, vl;
#pragma unroll
    for (int j = 0; j < 8; ++j) {
        int k = kbase + j;
        float val;
        if (c < 2) {
            val = dside[c * DIM + f] * RW[f * DIM + k] * dside[c * DIM + k];
        } else {
            val = Wrel[(size_t)(c - 2) * DIM * DIM + f * DIM + k];
        }
        short hi = f2bf_rn(val);
        float rem = val - bf2f(hi);
        vh[j] = hi;
        vl[j] = f2bf_rn(rem);
    }
    ((bf16x8*)Bh)[t] = vh;
    ((bf16x8*)Bl)[t] = vl;
}

// ---------------------------------------------------------------------------
// Fused edge kernel (round-4 envelope: 2 blocks/CU, no spill), with:
//  - A staging: one coalesced 1KB dwordx4 per gathered row (8 line-probes vs
//    32 scattered), split-bf16 packed u32(hi|lo), row-major LDS (stride 260
//    u32 == 4 mod 32 -> uniform bank spread for writes AND b128 K-loop reads)
//  - K-loop: A frags read straight from row-major LDS (no transpose), B frags
//    from pre-swizzled L2-resident table, 3-term split-bf16 MFMA
//  - V epilogue: dst rows re-staged coalesced into the SAME LDS buffer after
//    the K-loop; epilogue reads V from LDS (replaces scattered scalar gathers)
// ---------------------------------------------------------------------------
__global__ __launch_bounds__(256, 2)
void edge_kernel(const float* __restrict__ hmat,
                 const int* __restrict__ src_idx,
                 const int* __restrict__ dst_idx,
                 const float* __restrict__ brel,
                 const short* __restrict__ Bh_sw,
                 const short* __restrict__ Bl_sw,
                 float* __restrict__ out) {
    const int c    = blockIdx.y;
    const int e0   = blockIdx.x * ET;
    const int tid  = threadIdx.x;
    const int w    = tid >> 6;
    const int lane = tid & 63;
    const int quad = lane >> 4, col = lane & 15;

    __shared__ uint32_t s_row[ET * RS];      // 66,560 B (A packed, then V raw)
    __shared__ uint32_t s_src[ET];
    __shared__ uint32_t s_dst[ET];
    __shared__ float    red[4][ET];

    if (tid < ET) {
        int idx = e0 + tid;
        int si = 0, di = 0;
        if (idx < NEDGES) {
            si = src_idx[(size_t)c * NEDGES + idx];
            di = dst_idx[(size_t)c * NEDGES + idx];
        }
        s_src[tid] = (uint32_t)si;
        s_dst[tid] = (uint32_t)di;
    }
    __syncthreads();

    // ---- Stage A: wave w loads rows w*16..w*16+15, coalesced, split-pack ----
#pragma unroll
    for (int i = 0; i < 16; ++i) {
        int lr = w * 16 + i;
        const float* rb = hmat + (size_t)s_src[lr] * DIM;
        f32x4 x = *(const f32x4*)(rb + lane * 4);
        u32x4 o;
#pragma unroll
        for (int j = 0; j < 4; ++j) {
            short hi = f2bf_rn(x[j]);
            short lo = f2bf_rn(x[j] - bf2f(hi));
            o[j] = ((uint32_t)(unsigned short)hi << 16) | (uint32_t)(unsigned short)lo;
        }
        *(u32x4*)&s_row[lr * RS + lane * 4] = o;
    }
    __syncthreads();

    // ---- K-loop: A from row-major LDS, B from global, 3-term split MFMA ----
    f32x4 acc[4][4];
#pragma unroll
    for (int i = 0; i < 4; ++i)
#pragma unroll
        for (int j = 0; j < 4; ++j) acc[i][j] = (f32x4){0.f, 0.f, 0.f, 0.f};

    const bf16x8* Bh = (const bf16x8*)Bh_sw;
    const bf16x8* Bl = (const bf16x8*)Bl_sw;

#pragma unroll
    for (int kc = 0; kc < 8; ++kc) {
        bf16x8 Ah[4], Al[4];
#pragma unroll
        for (int mt = 0; mt < 4; ++mt) {
            const uint32_t* p = &s_row[(mt * 16 + col) * RS + kc * 32 + quad * 8];
            u32x4 q0 = *(const u32x4*)p;
            u32x4 q1 = *(const u32x4*)(p + 4);
            bf16x8 ah, al;
#pragma unroll
            for (int j = 0; j < 4; ++j) {
                ah[j]     = (short)(q0[j] >> 16);
                al[j]     = (short)(q0[j] & 0xffffu);
                ah[4 + j] = (short)(q1[j] >> 16);
                al[4 + j] = (short)(q1[j] & 0xffffu);
            }
            Ah[mt] = ah;
            Al[mt] = al;
        }
        int fb = ((c * 8 + kc) * 16 + w * 4) * 64 + lane;
#pragma unroll
        for (int ft = 0; ft < 4; ++ft) {
            bf16x8 bh = Bh[fb + ft * 64];
            bf16x8 bl = Bl[fb + ft * 64];
#pragma unroll
            for (int mt = 0; mt < 4; ++mt) {
                acc[mt][ft] = __builtin_amdgcn_mfma_f32_16x16x32_bf16(Ah[mt], bh, acc[mt][ft], 0, 0, 0);
                acc[mt][ft] = __builtin_amdgcn_mfma_f32_16x16x32_bf16(Ah[mt], bl, acc[mt][ft], 0, 0, 0);
                acc[mt][ft] = __builtin_amdgcn_mfma_f32_16x16x32_bf16(Al[mt], bh, acc[mt][ft], 0, 0, 0);
            }
        }
    }
    __syncthreads();   // all waves done reading A from s_row

    // ---- Stage V: dst rows, raw f32 bits, same coalesced pattern ----
#pragma unroll
    for (int i = 0; i < 16; ++i) {
        int lr = w * 16 + i;
        const float* rb = hmat + (size_t)s_dst[lr] * DIM;
        f32x4 x = *(const f32x4*)(rb + lane * 4);
        u32x4 o;
#pragma unroll
        for (int j = 0; j < 4; ++j) {
            union { float f; uint32_t u; } cv; cv.f = x[j]; o[j] = cv.u;
        }
        *(u32x4*)&s_row[lr * RS + lane * 4] = o;
    }
    __syncthreads();

    // ---- Epilogue: score_e = sum_f (C[e][f] + bias[f]) * V[e][f] ----
    // C/D layout: row(e) = quad*4 + reg, col(f) = lane&15. V from LDS (f32).
    float bias[4];
#pragma unroll
    for (int ft = 0; ft < 4; ++ft) {
        int f = w * 64 + ft * 16 + col;
        bias[ft] = (c >= 2) ? brel[(size_t)(c - 2) * DIM + f] : 0.f;
    }

    float psum[4][4];  // [mt][r]
#pragma unroll
    for (int mt = 0; mt < 4; ++mt) {
#pragma unroll
        for (int r = 0; r < 4; ++r) {
            int el = mt * 16 + quad * 4 + r;
            float s = 0.f;
#pragma unroll
            for (int ft = 0; ft < 4; ++ft) {
                int f = w * 64 + ft * 16 + col;
                float v = asf(s_row[el * RS + f]);
                s += (acc[mt][ft][r] + bias[ft]) * v;
            }
            psum[mt][r] = s;
        }
    }

    // Reduce across the 16 f-columns (xor lane bits 0..3)
#pragma unroll
    for (int off = 1; off < 16; off <<= 1) {
#pragma unroll
        for (int mt = 0; mt < 4; ++mt)
#pragma unroll
            for (int r = 0; r < 4; ++r)
                psum[mt][r] += __shfl_xor(psum[mt][r], off, 64);
    }
    if (col == 0) {
#pragma unroll
        for (int mt = 0; mt < 4; ++mt)
#pragma unroll
            for (int r = 0; r < 4; ++r)
                red[w][mt * 16 + quad * 4 + r] = psum[mt][r];
    }
    __syncthreads();

    if (tid < ET) {
        int idx = e0 + tid;
        if (idx < NEDGES) {
            float s = red[0][tid] + red[1][tid] + red[2][tid] + red[3][tid];
            out[(size_t)c * NEDGES + idx] = s;
        }
    }
}

extern "C" void kernel_launch(void* const* d_in, const int* in_sizes, int n_in,
                              void* d_out, int out_size, void* d_ws, size_t ws_size,
                              hipStream_t stream) {
    const float* hmat  = (const float*)d_in[0];
    const int*   src   = (const int*)d_in[1];
    const int*   dst   = (const int*)d_in[2];
    const float* RW    = (const float*)d_in[3];
    const float* dside = (const float*)d_in[4];
    const float* Wrel  = (const float*)d_in[5];
    const float* brel  = (const float*)d_in[6];
    float* out = (float*)d_out;

    // Workspace: Bh (512 KB) | Bl (512 KB)
    const size_t nB = (size_t)NCH * DIM * DIM;   // shorts per table
    short* Bh = (short*)d_ws;
    short* Bl = Bh + nB;

    prep_B<<<dim3((NCH * 8 * 16 * 64) / 256), dim3(256), 0, stream>>>(RW, dside, Wrel, Bh, Bl);

    dim3 grid((NEDGES + ET - 1) / ET, NCH);
    edge_kernel<<<grid, dim3(256), 0, stream>>>(hmat, src, dst, brel, Bh, Bl, out);
}

// Round 7
// 334.538 us; speedup vs baseline: 3.7856x; 1.0630x over previous
//
#include <hip/hip_runtime.h>
#include <stdint.h>

#define NNODES 100000
#define NEDGES 100000
#define DIM    256
#define NCH    4          // 2 side + 2 rel
#define ET     32         // edges per block (32 -> 34 KB LDS -> 4 blocks/CU)
#define RS     260        // u32 per staged row (256 + 4 pad; 260 % 32 == 4)

typedef short bf16x8 __attribute__((ext_vector_type(8)));
typedef float f32x4  __attribute__((ext_vector_type(4)));
typedef uint32_t u32x4 __attribute__((ext_vector_type(4)));

__device__ __forceinline__ short f2bf_rn(float x) {
    union { float f; uint32_t u; } v; v.f = x;
    uint32_t u = v.u;
    uint32_t r = u + 0x7fffu + ((u >> 16) & 1u);
    return (short)(r >> 16);
}
__device__ __forceinline__ float bf2f(short s) {
    union { float f; uint32_t u; } v;
    v.u = ((uint32_t)(unsigned short)s) << 16;
    return v.f;
}
__device__ __forceinline__ float asf(uint32_t u) {
    union { float f; uint32_t u; } v; v.u = u; return v.f;
}

// ---------------------------------------------------------------------------
// Prep: fused/transposed channel matrices in MFMA B-fragment order, split
// hi/lo bf16. idx = (((c*8+kc)*16+ft)*64+lane)*8+j,
// k = kc*32 + (lane>>4)*8 + j, f = ft*16 + (lane&15).
//   M_c[f][k] = d_side[c][f]*R_W[f][k]*d_side[c][k]   (c < 2)
//             = W_rel[c-2][f][k]                       (c >= 2)
// ---------------------------------------------------------------------------
__global__ void prep_B(const float* __restrict__ RW,
                       const float* __restrict__ dside,
                       const float* __restrict__ Wrel,
                       short* __restrict__ Bh, short* __restrict__ Bl) {
    int t = blockIdx.x * blockDim.x + threadIdx.x;
    if (t >= NCH * 8 * 16 * 64) return;
    int lane = t & 63;
    int ft   = (t >> 6) & 15;
    int kc   = (t >> 10) & 7;
    int c    = t >> 13;
    int quad = lane >> 4, col = lane & 15;
    int f     = ft * 16 + col;
    int kbase = kc * 32 + quad * 8;

    bf16x8 vh, vl;
#pragma unroll
    for (int j = 0; j < 8; ++j) {
        int k = kbase + j;
        float val;
        if (c < 2) {
            val = dside[c * DIM + f] * RW[f * DIM + k] * dside[c * DIM + k];
        } else {
            val = Wrel[(size_t)(c - 2) * DIM * DIM + f * DIM + k];
        }
        short hi = f2bf_rn(val);
        float rem = val - bf2f(hi);
        vh[j] = hi;
        vl[j] = f2bf_rn(rem);
    }
    ((bf16x8*)Bh)[t] = vh;
    ((bf16x8*)Bl)[t] = vl;
}

// ---------------------------------------------------------------------------
// Fused edge kernel, 32-edge tiles for 4 blocks/CU (16 waves/CU):
//  - A staging: 8 rows/wave, one coalesced 1KB dwordx4 per gathered row,
//    split-bf16 packed u32(hi|lo), row-major LDS (stride 260 u32)
//  - K-loop: A frags from row-major LDS (no transpose), B frags from the
//    pre-swizzled L2-resident table, 3-term split-bf16 MFMA, acc 2mt x 4ft
//  - V epilogue: dst rows re-staged coalesced into the SAME LDS after the
//    K-loop; epilogue reads V from LDS
// launch_bounds(256,2): do NOT force 4 waves/EU — R5 showed the allocator
// spills at a 64-VGPR cap. Natural VGPR (~70-90) <= 128 lets the HW reach
// the LDS-limited 4 blocks/CU on its own.
// ---------------------------------------------------------------------------
__global__ __launch_bounds__(256, 2)
void edge_kernel(const float* __restrict__ hmat,
                 const int* __restrict__ src_idx,
                 const int* __restrict__ dst_idx,
                 const float* __restrict__ brel,
                 const short* __restrict__ Bh_sw,
                 const short* __restrict__ Bl_sw,
                 float* __restrict__ out) {
    const int c    = blockIdx.y;
    const int e0   = blockIdx.x * ET;
    const int tid  = threadIdx.x;
    const int w    = tid >> 6;
    const int lane = tid & 63;
    const int quad = lane >> 4, col = lane & 15;

    __shared__ uint32_t s_row[ET * RS];      // 33,280 B (A packed, then V raw)
    __shared__ uint32_t s_src[ET];
    __shared__ uint32_t s_dst[ET];
    __shared__ float    red[4][ET];

    if (tid < ET) {
        int idx = e0 + tid;
        int si = 0, di = 0;
        if (idx < NEDGES) {
            si = src_idx[(size_t)c * NEDGES + idx];
            di = dst_idx[(size_t)c * NEDGES + idx];
        }
        s_src[tid] = (uint32_t)si;
        s_dst[tid] = (uint32_t)di;
    }
    __syncthreads();

    // ---- Stage A: wave w loads rows w*8..w*8+7, coalesced, split-pack ----
#pragma unroll
    for (int i = 0; i < 8; ++i) {
        int lr = w * 8 + i;
        const float* rb = hmat + (size_t)s_src[lr] * DIM;
        f32x4 x = *(const f32x4*)(rb + lane * 4);
        u32x4 o;
#pragma unroll
        for (int j = 0; j < 4; ++j) {
            short hi = f2bf_rn(x[j]);
            short lo = f2bf_rn(x[j] - bf2f(hi));
            o[j] = ((uint32_t)(unsigned short)hi << 16) | (uint32_t)(unsigned short)lo;
        }
        *(u32x4*)&s_row[lr * RS + lane * 4] = o;
    }
    __syncthreads();

    // ---- K-loop: A from row-major LDS, B from global, 3-term split MFMA ----
    f32x4 acc[2][4];
#pragma unroll
    for (int i = 0; i < 2; ++i)
#pragma unroll
        for (int j = 0; j < 4; ++j) acc[i][j] = (f32x4){0.f, 0.f, 0.f, 0.f};

    const bf16x8* Bh = (const bf16x8*)Bh_sw;
    const bf16x8* Bl = (const bf16x8*)Bl_sw;

#pragma unroll
    for (int kc = 0; kc < 8; ++kc) {
        bf16x8 Ah[2], Al[2];
#pragma unroll
        for (int mt = 0; mt < 2; ++mt) {
            const uint32_t* p = &s_row[(mt * 16 + col) * RS + kc * 32 + quad * 8];
            u32x4 q0 = *(const u32x4*)p;
            u32x4 q1 = *(const u32x4*)(p + 4);
            bf16x8 ah, al;
#pragma unroll
            for (int j = 0; j < 4; ++j) {
                ah[j]     = (short)(q0[j] >> 16);
                al[j]     = (short)(q0[j] & 0xffffu);
                ah[4 + j] = (short)(q1[j] >> 16);
                al[4 + j] = (short)(q1[j] & 0xffffu);
            }
            Ah[mt] = ah;
            Al[mt] = al;
        }
        int fb = ((c * 8 + kc) * 16 + w * 4) * 64 + lane;
#pragma unroll
        for (int ft = 0; ft < 4; ++ft) {
            bf16x8 bh = Bh[fb + ft * 64];
            bf16x8 bl = Bl[fb + ft * 64];
#pragma unroll
            for (int mt = 0; mt < 2; ++mt) {
                acc[mt][ft] = __builtin_amdgcn_mfma_f32_16x16x32_bf16(Ah[mt], bh, acc[mt][ft], 0, 0, 0);
                acc[mt][ft] = __builtin_amdgcn_mfma_f32_16x16x32_bf16(Ah[mt], bl, acc[mt][ft], 0, 0, 0);
                acc[mt][ft] = __builtin_amdgcn_mfma_f32_16x16x32_bf16(Al[mt], bh, acc[mt][ft], 0, 0, 0);
            }
        }
    }
    __syncthreads();   // all waves done reading A from s_row

    // ---- Stage V: dst rows, raw f32 bits, same coalesced pattern ----
#pragma unroll
    for (int i = 0; i < 8; ++i) {
        int lr = w * 8 + i;
        const float* rb = hmat + (size_t)s_dst[lr] * DIM;
        f32x4 x = *(const f32x4*)(rb + lane * 4);
        u32x4 o;
#pragma unroll
        for (int j = 0; j < 4; ++j) {
            union { float f; uint32_t u; } cv; cv.f = x[j]; o[j] = cv.u;
        }
        *(u32x4*)&s_row[lr * RS + lane * 4] = o;
    }
    __syncthreads();

    // ---- Epilogue: score_e = sum_f (C[e][f] + bias[f]) * V[e][f] ----
    // C/D layout: row(e) = quad*4 + reg, col(f) = lane&15. V from LDS (f32).
    float bias[4];
#pragma unroll
    for (int ft = 0; ft < 4; ++ft) {
        int f = w * 64 + ft * 16 + col;
        bias[ft] = (c >= 2) ? brel[(size_t)(c - 2) * DIM + f] : 0.f;
    }

    float psum[2][4];  // [mt][r]
#pragma unroll
    for (int mt = 0; mt < 2; ++mt) {
#pragma unroll
        for (int r = 0; r < 4; ++r) {
            int el = mt * 16 + quad * 4 + r;
            float s = 0.f;
#pragma unroll
            for (int ft = 0; ft < 4; ++ft) {
                int f = w * 64 + ft * 16 + col;
                float v = asf(s_row[el * RS + f]);
                s += (acc[mt][ft][r] + bias[ft]) * v;
            }
            psum[mt][r] = s;
        }
    }

    // Reduce across the 16 f-columns (xor lane bits 0..3)
#pragma unroll
    for (int off = 1; off < 16; off <<= 1) {
#pragma unroll
        for (int mt = 0; mt < 2; ++mt)
#pragma unroll
            for (int r = 0; r < 4; ++r)
                psum[mt][r] += __shfl_xor(psum[mt][r], off, 64);
    }
    if (col == 0) {
#pragma unroll
        for (int mt = 0; mt < 2; ++mt)
#pragma unroll
            for (int r = 0; r < 4; ++r)
                red[w][mt * 16 + quad * 4 + r] = psum[mt][r];
    }
    __syncthreads();

    if (tid < ET) {
        int idx = e0 + tid;
        if (idx < NEDGES) {
            float s = red[0][tid] + red[1][tid] + red[2][tid] + red[3][tid];
            out[(size_t)c * NEDGES + idx] = s;
        }
    }
}

extern "C" void kernel_launch(void* const* d_in, const int* in_sizes, int n_in,
                              void* d_out, int out_size, void* d_ws, size_t ws_size,
                              hipStream_t stream) {
    const float* hmat  = (const float*)d_in[0];
    const int*   src   = (const int*)d_in[1];
    const int*   dst   = (const int*)d_in[2];
    const float* RW    = (const float*)d_in[3];
    const float* dside = (const float*)d_in[4];
    const float* Wrel  = (const float*)d_in[5];
    const float* brel  = (const float*)d_in[6];
    float* out = (float*)d_out;

    // Workspace: Bh (512 KB) | Bl (512 KB)
    const size_t nB = (size_t)NCH * DIM * DIM;   // shorts per table
    short* Bh = (short*)d_ws;
    short* Bl = Bh + nB;

    prep_B<<<dim3((NCH * 8 * 16 * 64) / 256), dim3(256), 0, stream>>>(RW, dside, Wrel, Bh, Bl);

    dim3 grid((NEDGES + ET - 1) / ET, NCH);
    edge_kernel<<<grid, dim3(256), 0, stream>>>(hmat, src, dst, brel, Bh, Bl, out);
}

// Round 8
// 311.811 us; speedup vs baseline: 4.0615x; 1.0729x over previous
//
#include <hip/hip_runtime.h>
#include <stdint.h>

#define NNODES 100000
#define NEDGES 100000
#define DIM    256
#define NCH    4          // 2 side + 2 rel
#define ET     32         // edges per block
#define RSF    264        // fp16 per staged row (256 + 8 pad; 264*2B=528B, 528/4=132 dw == 4 mod 32)

typedef _Float16 f16x8 __attribute__((ext_vector_type(8)));
typedef _Float16 f16x4 __attribute__((ext_vector_type(4)));
typedef float f32x4  __attribute__((ext_vector_type(4)));

// ---------------------------------------------------------------------------
// Fused prep (single launch):
//  blocks [0,128):  build the 4 fused/transposed channel matrices in MFMA
//    B-fragment order, split into fp16 hi/lo (22-bit effective).
//    idx = (((c*8+kc)*16+ft)*64+lane)*8+j ;  k = kc*32+(lane>>4)*8+j,
//    f = ft*16+(lane&15).
//      M_c[f][k] = d_side[c][f]*R_W[f][k]*d_side[c][k]  (c<2)
//                = W_rel[c-2][f][k]                      (c>=2)
//  blocks [128, 128+12500): convert h (f32, 102 MB) -> fp16 array (51 MB).
//    h ~ N(0,1): well inside fp16 range; fp16 keeps 10 mantissa bits.
// ---------------------------------------------------------------------------
__global__ void prep_fused(const float* __restrict__ RW,
                           const float* __restrict__ dside,
                           const float* __restrict__ Wrel,
                           const float* __restrict__ h,
                           _Float16* __restrict__ Bh, _Float16* __restrict__ Bl,
                           _Float16* __restrict__ H16) {
    if (blockIdx.x < 128) {
        int t = blockIdx.x * blockDim.x + threadIdx.x;   // < 32768
        int lane = t & 63;
        int ft   = (t >> 6) & 15;
        int kc   = (t >> 10) & 7;
        int c    = t >> 13;
        int quad = lane >> 4, col = lane & 15;
        int f     = ft * 16 + col;
        int kbase = kc * 32 + quad * 8;

        f16x8 vh, vl;
#pragma unroll
        for (int j = 0; j < 8; ++j) {
            int k = kbase + j;
            float val;
            if (c < 2) {
                val = dside[c * DIM + f] * RW[f * DIM + k] * dside[c * DIM + k];
            } else {
                val = Wrel[(size_t)(c - 2) * DIM * DIM + f * DIM + k];
            }
            _Float16 hi = (_Float16)val;
            vh[j] = hi;
            vl[j] = (_Float16)(val - (float)hi);
        }
        ((f16x8*)Bh)[t] = vh;
        ((f16x8*)Bl)[t] = vl;
    } else {
        int u = (blockIdx.x - 128) * blockDim.x + threadIdx.x;  // 8 elems each
        if (u >= NNODES * DIM / 8) return;
        f32x4 x0 = ((const f32x4*)h)[2 * u];
        f32x4 x1 = ((const f32x4*)h)[2 * u + 1];
        f16x8 o;
#pragma unroll
        for (int j = 0; j < 4; ++j) {
            o[j]     = (_Float16)x0[j];
            o[4 + j] = (_Float16)x1[j];
        }
        ((f16x8*)H16)[u] = o;
    }
}

// ---------------------------------------------------------------------------
// Fused edge kernel, fp16 gathers (halved external gather bytes = the wall):
//  - A staging: 8 rows/wave, coalesced 512B row loads from fp16 h, straight
//    copy into row-major LDS (no conversion VALU at all)
//  - K-loop: A frags = single ds_read_b128 each (LDS row IS the fragment
//    layout), B fp16 hi/lo from pre-swizzled L2-resident table, 2-term
//    f16 MFMA: acc = A*Bh + A*Bl  (A 11-bit, B 22-bit effective)
//  - V epilogue: dst rows re-staged (fp16) into same LDS; score in fp32.
// LDS ~18 KB -> many blocks/CU. launch_bounds(256,2): let the allocator
// pick natural VGPRs (R5 lesson: never force it down).
// ---------------------------------------------------------------------------
__global__ __launch_bounds__(256, 2)
void edge_kernel(const _Float16* __restrict__ H16,
                 const int* __restrict__ src_idx,
                 const int* __restrict__ dst_idx,
                 const float* __restrict__ brel,
                 const _Float16* __restrict__ Bh_sw,
                 const _Float16* __restrict__ Bl_sw,
                 float* __restrict__ out) {
    const int c    = blockIdx.y;
    const int e0   = blockIdx.x * ET;
    const int tid  = threadIdx.x;
    const int w    = tid >> 6;
    const int lane = tid & 63;
    const int quad = lane >> 4, col = lane & 15;

    __shared__ __align__(16) _Float16 s_row[ET * RSF];   // 16,896 B
    __shared__ uint32_t s_src[ET];
    __shared__ uint32_t s_dst[ET];
    __shared__ float    red[4][ET];

    if (tid < ET) {
        int idx = e0 + tid;
        int si = 0, di = 0;
        if (idx < NEDGES) {
            si = src_idx[(size_t)c * NEDGES + idx];
            di = dst_idx[(size_t)c * NEDGES + idx];
        }
        s_src[tid] = (uint32_t)si;
        s_dst[tid] = (uint32_t)di;
    }
    __syncthreads();

    // ---- Stage A: wave w copies rows w*8..w*8+7 (512 B coalesced each) ----
#pragma unroll
    for (int i = 0; i < 8; ++i) {
        int lr = w * 8 + i;
        const _Float16* rb = H16 + (size_t)s_src[lr] * DIM;
        f16x4 x = *(const f16x4*)(rb + lane * 4);
        *(f16x4*)&s_row[lr * RSF + lane * 4] = x;
    }
    __syncthreads();

    // ---- K-loop: A from LDS (direct fragment reads), 2-term f16 MFMA ----
    f32x4 acc[2][4];
#pragma unroll
    for (int i = 0; i < 2; ++i)
#pragma unroll
        for (int j = 0; j < 4; ++j) acc[i][j] = (f32x4){0.f, 0.f, 0.f, 0.f};

    const f16x8* Bh = (const f16x8*)Bh_sw;
    const f16x8* Bl = (const f16x8*)Bl_sw;

#pragma unroll
    for (int kc = 0; kc < 8; ++kc) {
        f16x8 A[2];
#pragma unroll
        for (int mt = 0; mt < 2; ++mt)
            A[mt] = *(const f16x8*)&s_row[(mt * 16 + col) * RSF + kc * 32 + quad * 8];

        int fb = ((c * 8 + kc) * 16 + w * 4) * 64 + lane;
#pragma unroll
        for (int ft = 0; ft < 4; ++ft) {
            f16x8 bh = Bh[fb + ft * 64];
            f16x8 bl = Bl[fb + ft * 64];
#pragma unroll
            for (int mt = 0; mt < 2; ++mt) {
                acc[mt][ft] = __builtin_amdgcn_mfma_f32_16x16x32_f16(A[mt], bh, acc[mt][ft], 0, 0, 0);
                acc[mt][ft] = __builtin_amdgcn_mfma_f32_16x16x32_f16(A[mt], bl, acc[mt][ft], 0, 0, 0);
            }
        }
    }
    __syncthreads();   // all waves done reading A from s_row

    // ---- Stage V: dst rows (fp16), same coalesced copy ----
#pragma unroll
    for (int i = 0; i < 8; ++i) {
        int lr = w * 8 + i;
        const _Float16* rb = H16 + (size_t)s_dst[lr] * DIM;
        f16x4 x = *(const f16x4*)(rb + lane * 4);
        *(f16x4*)&s_row[lr * RSF + lane * 4] = x;
    }
    __syncthreads();

    // ---- Epilogue: score_e = sum_f (C[e][f] + bias[f]) * V[e][f] ----
    // C/D layout: row(e) = quad*4 + reg, col(f) = lane&15.
    float bias[4];
#pragma unroll
    for (int ft = 0; ft < 4; ++ft) {
        int f = w * 64 + ft * 16 + col;
        bias[ft] = (c >= 2) ? brel[(size_t)(c - 2) * DIM + f] : 0.f;
    }

    float psum[2][4];  // [mt][r]
#pragma unroll
    for (int mt = 0; mt < 2; ++mt) {
#pragma unroll
        for (int r = 0; r < 4; ++r) {
            int el = mt * 16 + quad * 4 + r;
            float s = 0.f;
#pragma unroll
            for (int ft = 0; ft < 4; ++ft) {
                int f = w * 64 + ft * 16 + col;
                float v = (float)s_row[el * RSF + f];
                s += (acc[mt][ft][r] + bias[ft]) * v;
            }
            psum[mt][r] = s;
        }
    }

    // Reduce across the 16 f-columns (xor lane bits 0..3)
#pragma unroll
    for (int off = 1; off < 16; off <<= 1) {
#pragma unroll
        for (int mt = 0; mt < 2; ++mt)
#pragma unroll
            for (int r = 0; r < 4; ++r)
                psum[mt][r] += __shfl_xor(psum[mt][r], off, 64);
    }
    if (col == 0) {
#pragma unroll
        for (int mt = 0; mt < 2; ++mt)
#pragma unroll
            for (int r = 0; r < 4; ++r)
                red[w][mt * 16 + quad * 4 + r] = psum[mt][r];
    }
    __syncthreads();

    if (tid < ET) {
        int idx = e0 + tid;
        if (idx < NEDGES) {
            float s = red[0][tid] + red[1][tid] + red[2][tid] + red[3][tid];
            out[(size_t)c * NEDGES + idx] = s;
        }
    }
}

extern "C" void kernel_launch(void* const* d_in, const int* in_sizes, int n_in,
                              void* d_out, int out_size, void* d_ws, size_t ws_size,
                              hipStream_t stream) {
    const float* hmat  = (const float*)d_in[0];
    const int*   src   = (const int*)d_in[1];
    const int*   dst   = (const int*)d_in[2];
    const float* RW    = (const float*)d_in[3];
    const float* dside = (const float*)d_in[4];
    const float* Wrel  = (const float*)d_in[5];
    const float* brel  = (const float*)d_in[6];
    float* out = (float*)d_out;

    // Workspace: Bh (512 KB) | Bl (512 KB) | H16 (51.2 MB)
    const size_t nB = (size_t)NCH * DIM * DIM;   // fp16 per table
    _Float16* Bh  = (_Float16*)d_ws;
    _Float16* Bl  = Bh + nB;
    _Float16* H16 = Bl + nB;

    const int convBlocks = (NNODES * DIM / 8 + 255) / 256;   // 12500
    prep_fused<<<dim3(128 + convBlocks), dim3(256), 0, stream>>>(
        RW, dside, Wrel, hmat, Bh, Bl, H16);

    dim3 grid((NEDGES + ET - 1) / ET, NCH);
    edge_kernel<<<grid, dim3(256), 0, stream>>>(H16, src, dst, brel, Bh, Bl, out);
}